// Round 3
// baseline (178.886 us; speedup 1.0000x reference)
//
#include <hip/hip_runtime.h>

// QuestionFlowLayer: out[i] = concat(q[i], mean(q[0:i])) for q [1024, 64, 1024] f32.
//
// Minimal-traffic single-pass block-scan:
//  - Block = 256 threads (4 waves) owns 64 consecutive scalar columns; each of
//    the 4 waves covers those SAME 64 columns for a different 64-row chunk.
//  - N=1024 split into 4 super-steps of 256 rows. Per super-step: each wave
//    loads its 64 rows into registers (64 independent loads in flight),
//    computes its chunk sum, exchanges the 4 chunk sums via LDS, then emits
//    its 64 output rows (v + running-prefix mean) from registers.
//  - Input read once (268 MB), output written once (537 MB). 1024 blocks ->
//    16 waves/CU, vs 4 waves/CU in the previous one-thread-per-column scan.
constexpr int N_TURNS = 1024;
constexpr int D_MOD   = 1024;
constexpr unsigned COLS = 65536;            // L*D scalar columns
constexpr unsigned OUT_ROW = 2u * 64 * D_MOD; // floats per turn in out: 131072

constexpr int WAVES = 4;
constexpr int RPW   = 64;                   // rows per wave per super-step
constexpr int SUPER = N_TURNS / (WAVES * RPW); // 4 super-steps

__global__ __launch_bounds__(256, 4) void qflow_block_scan(
        const float* __restrict__ q, float* __restrict__ out) {
    __shared__ float csum[WAVES][64];

    const unsigned lane = threadIdx.x & 63u;
    const unsigned w    = threadIdx.x >> 6;       // wave id within block
    const unsigned c    = blockIdx.x * 64u + lane; // scalar column
    const unsigned l    = c >> 10;
    const unsigned d    = c & (D_MOD - 1u);

    const float* qp = q + c;                       // q[i][c] = qp[i*COLS]
    // Bias by +512 floats (+2048 B): v at byte offset -2048, avg at +2048,
    // both within the 13-bit signed global_store immediate from one address.
    float* opb = out + (size_t)l * (2u * D_MOD) + d + 512u;

    float superPrefix = 0.0f;

    for (unsigned s = 0; s < SUPER; ++s) {
        const unsigned base = s * (WAVES * RPW) + w * RPW; // first row of my chunk
        float v[RPW];

        // Phase 1: pure loads (all independent; deep in flight).
        #pragma unroll
        for (int j = 0; j < RPW; ++j) {
            v[j] = qp[(size_t)(base + j) * COLS];
        }
        // Chunk sum (tree-ish via compiler; order diff vs ref is << threshold).
        float chunk = 0.0f;
        #pragma unroll
        for (int j = 0; j < RPW; ++j) chunk += v[j];

        csum[w][lane] = chunk;
        __syncthreads();

        // Exclusive prefix over the 4 wave-chunks + total for next super-step.
        float run = superPrefix;
        float total = 0.0f;
        #pragma unroll
        for (int w2 = 0; w2 < WAVES; ++w2) {
            float t = csum[w2][lane];
            if ((unsigned)w2 < w) run += t;
            total += t;
        }
        __syncthreads();  // LDS reused next super-step

        // Phase 2: emit 64 rows (pure stores).
        #pragma unroll
        for (int j = 0; j < RPW; ++j) {
            const unsigned i = base + j;
            const float inv = (i == 0) ? 0.0f : __builtin_amdgcn_rcpf((float)i);
            const float avg = run * inv;
            const size_t ob = (size_t)i * OUT_ROW;
            opb[ob - 512] = v[j];      // out[i][l][d]
            opb[ob + 512] = avg;       // out[i][l][D+d]
            run += v[j];
        }
        superPrefix += total;
    }
}

extern "C" void kernel_launch(void* const* d_in, const int* in_sizes, int n_in,
                              void* d_out, int out_size, void* d_ws, size_t ws_size,
                              hipStream_t stream) {
    const float* q = (const float*)d_in[0];
    float* out = (float*)d_out;
    qflow_block_scan<<<COLS / 64, 256, 0, stream>>>(q, out);
}